// Round 1
// baseline (725.116 us; speedup 1.0000x reference)
//
#include <hip/hip_runtime.h>
#include <hip/hip_bf16.h>

// Problem constants (fixed by reference)
constexpr int Bb = 8, Hh = 32, Ss = 1024, Dd = 128, ML = 2048;
constexpr int QT = 64;    // q rows per block (16 per wave x 4 waves)
constexpr int KT = 32;    // kv rows per tile
constexpr int KSTR = 136; // K lds row stride in bf16 (pad: 272B -> 2-way max conflict)
constexpr int VSTR = 40;  // Vt row stride in bf16 (80B)
constexpr int PSTR = 40;  // P lds row stride

typedef __attribute__((ext_vector_type(8))) short bf16x8;
typedef __attribute__((ext_vector_type(4))) float f32x4;

__device__ __forceinline__ short f2bf(float x) {
    unsigned u = __builtin_bit_cast(unsigned, x);
    u = (u + 0x7fffu + ((u >> 16) & 1u)) >> 16; // RNE
    return (short)u;
}
__device__ __forceinline__ float bf2f(short s) {
    unsigned u = ((unsigned)(unsigned short)s) << 16;
    return __builtin_bit_cast(float, u);
}

__global__ __launch_bounds__(256, 4)
void attn_fwd(const float* __restrict__ Q, const float* __restrict__ KN,
              const float* __restrict__ VN, const float* __restrict__ KC,
              const float* __restrict__ VC, const int* __restrict__ CPOS,
              float* __restrict__ OUT)
{
    __shared__ __align__(16) short Klds[KT * KSTR];
    __shared__ __align__(16) short Vt[Dd * VSTR];
    __shared__ __align__(16) short Plds[4][16 * PSTR];

    const int tid = threadIdx.x;
    const int wv  = tid >> 6;
    const int ln64 = tid & 63;
    const int g  = ln64 >> 4;  // 16-lane group 0..3
    const int ln = ln64 & 15;  // lane within group

    const int bh = blockIdx.y;               // b*H + h
    const int q0 = blockIdx.x * QT + wv * 16; // this wave's first q row

    const int cpos = CPOS[0];
    const int endp = cpos + Ss;
    const int ntile = (endp + KT - 1) / KT;

    // ---- Q fragments: lane ln holds row (q0+ln), d = kk*32 + g*8 + i ----
    bf16x8 qf[4];
    {
        const float* qr = Q + ((size_t)bh * Ss + q0 + ln) * Dd + g * 8;
        #pragma unroll
        for (int kk = 0; kk < 4; ++kk) {
            float4 a = *(const float4*)(qr + kk * 32);
            float4 b = *(const float4*)(qr + kk * 32 + 4);
            bf16x8 f;
            f[0] = f2bf(a.x); f[1] = f2bf(a.y); f[2] = f2bf(a.z); f[3] = f2bf(a.w);
            f[4] = f2bf(b.x); f[5] = f2bf(b.y); f[6] = f2bf(b.z); f[7] = f2bf(b.w);
            qf[kk] = f;
        }
    }

    f32x4 O[8];
    #pragma unroll
    for (int t = 0; t < 8; ++t) O[t] = (f32x4){0.f, 0.f, 0.f, 0.f};
    float mrun[4], lrun[4];
    #pragma unroll
    for (int r = 0; r < 4; ++r) { mrun[r] = -1e30f; lrun[r] = 0.f; }

    // softmax in log2 domain: scores_log2 = acc * (1/sqrt(D) * log2(e))
    const float SCALE2 = 0.08838834764831845f * 1.44269504088896340736f;

    const int srow = tid >> 3;         // staging: row 0..31
    const int scol = (tid & 7) * 16;   // staging: 16 cols per thread

    for (int t = 0; t < ntile; ++t) {
        const int kv0 = t * KT;
        __syncthreads();
        // ---- stage K tile (row-major, padded) and V tile (transposed) ----
        {
            const int gkv = kv0 + srow;
            short kb[16], vb[16];
            if (gkv < endp) {
                const float *ksrc, *vsrc;
                if (gkv < cpos) {
                    ksrc = KC + ((size_t)bh * ML + gkv) * Dd + scol;
                    vsrc = VC + ((size_t)bh * ML + gkv) * Dd + scol;
                } else {
                    ksrc = KN + ((size_t)bh * Ss + (gkv - cpos)) * Dd + scol;
                    vsrc = VN + ((size_t)bh * Ss + (gkv - cpos)) * Dd + scol;
                }
                #pragma unroll
                for (int j = 0; j < 4; ++j) {
                    float4 k4 = ((const float4*)ksrc)[j];
                    float4 v4 = ((const float4*)vsrc)[j];
                    kb[j*4+0] = f2bf(k4.x); kb[j*4+1] = f2bf(k4.y);
                    kb[j*4+2] = f2bf(k4.z); kb[j*4+3] = f2bf(k4.w);
                    vb[j*4+0] = f2bf(v4.x); vb[j*4+1] = f2bf(v4.y);
                    vb[j*4+2] = f2bf(v4.z); vb[j*4+3] = f2bf(v4.w);
                }
            } else {
                #pragma unroll
                for (int j = 0; j < 16; ++j) { kb[j] = 0; vb[j] = 0; }
            }
            bf16x8 klo, khi;
            #pragma unroll
            for (int j = 0; j < 8; ++j) { klo[j] = kb[j]; khi[j] = kb[8+j]; }
            *(bf16x8*)(&Klds[srow * KSTR + scol])     = klo;
            *(bf16x8*)(&Klds[srow * KSTR + scol + 8]) = khi;
            #pragma unroll
            for (int j = 0; j < 16; ++j) Vt[(scol + j) * VSTR + srow] = vb[j];
        }
        __syncthreads();

        // ---- QK^T: scores for cols kv0 + h*16 + ln ----
        f32x4 sc[2];
        #pragma unroll
        for (int h = 0; h < 2; ++h) {
            f32x4 acc = (f32x4){0.f, 0.f, 0.f, 0.f};
            #pragma unroll
            for (int kk = 0; kk < 4; ++kk) {
                bf16x8 kf = *(const bf16x8*)(&Klds[(h*16 + ln) * KSTR + kk*32 + g*8]);
                acc = __builtin_amdgcn_mfma_f32_16x16x32_bf16(qf[kk], kf, acc, 0, 0, 0);
            }
            sc[h] = acc;
        }
        const bool v0 = (kv0 + ln) < endp;
        const bool v1 = (kv0 + 16 + ln) < endp;
        float s0[4], s1[4];
        #pragma unroll
        for (int r = 0; r < 4; ++r) {
            s0[r] = v0 ? sc[0][r] * SCALE2 : -1e30f;
            s1[r] = v1 ? sc[1][r] * SCALE2 : -1e30f;
        }

        // ---- online softmax (rows live on 16-lane groups; reg r -> row g*4+r) ----
        short pb0[4], pb1[4];
        float alpha[4];
        #pragma unroll
        for (int r = 0; r < 4; ++r) {
            float tm = fmaxf(s0[r], s1[r]);
            #pragma unroll
            for (int off = 1; off < 16; off <<= 1) tm = fmaxf(tm, __shfl_xor(tm, off));
            float mnew = fmaxf(mrun[r], tm);
            alpha[r] = exp2f(mrun[r] - mnew);
            mrun[r] = mnew;
            float p0 = exp2f(s0[r] - mnew);
            float p1 = exp2f(s1[r] - mnew);
            pb0[r] = f2bf(p0); pb1[r] = f2bf(p1);
            float rs = bf2f(pb0[r]) + bf2f(pb1[r]); // sum the *rounded* P
            #pragma unroll
            for (int off = 1; off < 16; off <<= 1) rs += __shfl_xor(rs, off);
            lrun[r] = lrun[r] * alpha[r] + rs;
        }
        #pragma unroll
        for (int tt = 0; tt < 8; ++tt)
            #pragma unroll
            for (int r = 0; r < 4; ++r) O[tt][r] *= alpha[r];

        // ---- P: C-layout (row g*4+r, col h*16+ln) -> LDS -> A-layout frag ----
        #pragma unroll
        for (int r = 0; r < 4; ++r) {
            Plds[wv][(g*4 + r) * PSTR + ln]      = pb0[r];
            Plds[wv][(g*4 + r) * PSTR + 16 + ln] = pb1[r];
        }
        bf16x8 af = *(const bf16x8*)(&Plds[wv][ln * PSTR + g * 8]);

        // ---- PV: O[tt] += P(16x32) x V(32x16) for 8 d-tiles ----
        #pragma unroll
        for (int tt = 0; tt < 8; ++tt) {
            bf16x8 vf = *(const bf16x8*)(&Vt[(tt*16 + ln) * VSTR + g * 8]);
            O[tt] = __builtin_amdgcn_mfma_f32_16x16x32_bf16(af, vf, O[tt], 0, 0, 0);
        }
    }

    // ---- epilogue: normalize and store ----
    float inv[4];
    #pragma unroll
    for (int r = 0; r < 4; ++r) inv[r] = 1.0f / lrun[r];
    float* ob = OUT + ((size_t)bh * Ss + q0) * Dd;
    #pragma unroll
    for (int tt = 0; tt < 8; ++tt)
        #pragma unroll
        for (int r = 0; r < 4; ++r)
            ob[(g*4 + r) * Dd + tt*16 + ln] = O[tt][r] * inv[r];
}

extern "C" void kernel_launch(void* const* d_in, const int* in_sizes, int n_in,
                              void* d_out, int out_size, void* d_ws, size_t ws_size,
                              hipStream_t stream) {
    const float* Q  = (const float*)d_in[0];
    const float* KN = (const float*)d_in[1];
    const float* VN = (const float*)d_in[2];
    const float* KC = (const float*)d_in[3];
    const float* VC = (const float*)d_in[4];
    const int* CPOS = (const int*)d_in[5];
    float* OUT = (float*)d_out;

    dim3 grid(Ss / QT, Bb * Hh);
    attn_fwd<<<grid, 256, 0, stream>>>(Q, KN, VN, KC, VC, CPOS, OUT);
}